// Round 1
// baseline (1547.786 us; speedup 1.0000x reference)
//
#include <hip/hip_runtime.h>
#include <hip/hip_bf16.h>

#define IN_DIM 64
#define H 128
#define G3 384
#define OUT_DIM 64
#define Bb 1024
#define Tt 512
#define NEG 0.01f
#define EPSLN 1e-5f

#define CHUNK 16
#define NCHUNK (Tt / CHUNK)

typedef __bf16 bf16_t;
typedef __bf16 bf16x8 __attribute__((ext_vector_type(8)));
typedef float f32x4 __attribute__((ext_vector_type(4)));

// ---- LDS layout (bytes), all 16B aligned ----
#define GX_OFF 0        // bf16 [64][392]  gates_x tile
#define GXS 392
#define HA_OFF 50176    // bf16 [64][136]  h1/h2/y staging
#define HAS 136
#define HPF_OFF 67584   // f32  [4][128]   h_prev fp32
#define HPB_OFF 69632   // bf16 [16][136]  h_prev bf16 (rows 4..15 zero)
#define RED_OFF 73984   // f32  [64][8]    LN cross-wave partials
#define MNR_OFF 76032   // f32  [64][2]    mean/rstd
#define GHB_OFF 76544   // f32  [4][388]   gh roundtrip
#define GHS 388
#define VEC_OFF 82752   // f32  [1600]     all bias/gain vectors
#define INI_OFF 89152   // int  [4][17]    init flags for chunk (+1 lookahead)
#define SMEM_BYTES 89440

#define V_B1 0
#define V_G1 128
#define V_BE1 256
#define V_B2 384
#define V_G2 512
#define V_BE2 640
#define V_BIH 768
#define V_BHH 1152
#define V_BOUT 1536

#define MFMA(a, b, c) __builtin_amdgcn_mfma_f32_16x16x32_bf16((a), (b), (c), 0, 0, 0)

__global__ void __launch_bounds__(256, 1) gru_fused(
    const float* __restrict__ x, const int* __restrict__ is_init,
    const float* __restrict__ hx,
    const float* __restrict__ W1, const float* __restrict__ b1,
    const float* __restrict__ g1, const float* __restrict__ be1,
    const float* __restrict__ W2, const float* __restrict__ b2,
    const float* __restrict__ g2, const float* __restrict__ be2,
    const float* __restrict__ Wih, const float* __restrict__ Whh,
    const float* __restrict__ bih, const float* __restrict__ bhh,
    const float* __restrict__ Wout, const float* __restrict__ bout,
    float* __restrict__ out)
{
    extern __shared__ char smem[];
    bf16_t* GX  = (bf16_t*)(smem + GX_OFF);
    bf16_t* HA  = (bf16_t*)(smem + HA_OFF);
    float*  HPF = (float*) (smem + HPF_OFF);
    bf16_t* HPB = (bf16_t*)(smem + HPB_OFF);
    float*  RED = (float*) (smem + RED_OFF);
    float*  MNR = (float*) (smem + MNR_OFF);
    float*  GHB = (float*) (smem + GHB_OFF);
    float*  VEC = (float*) (smem + VEC_OFF);
    int*    INI = (int*)   (smem + INI_OFF);

    const int tid  = threadIdx.x;
    const int w    = tid >> 6;        // wave 0..3
    const int lane = tid & 63;
    const int ln   = lane & 15;
    const int quad = lane >> 4;
    const int b0   = blockIdx.x * 4;  // 4 batch rows per block

    // ---- one-time setup ----
    for (int i = tid; i < H; i += 256) {
        VEC[V_B1 + i] = b1[i];  VEC[V_G1 + i] = g1[i];  VEC[V_BE1 + i] = be1[i];
        VEC[V_B2 + i] = b2[i];  VEC[V_G2 + i] = g2[i];  VEC[V_BE2 + i] = be2[i];
    }
    for (int i = tid; i < G3; i += 256) {
        VEC[V_BIH + i] = bih[i];  VEC[V_BHH + i] = bhh[i];
    }
    if (tid < OUT_DIM) VEC[V_BOUT + tid] = bout[tid];
    for (int i = tid; i < 16 * HAS; i += 256) HPB[i] = (bf16_t)0.f;
    __syncthreads();
    // h0 = is_init[b,0] ? 0 : hx[b]
    for (int job = tid; job < 512; job += 256) {
        int b = job >> 7, j = job & 127;
        int im = is_init[(size_t)(b0 + b) * Tt];
        float v = im ? 0.f : hx[(size_t)(b0 + b) * H + j];
        HPF[b * H + j] = v;
        HPB[b * HAS + j] = (bf16_t)v;
    }
    // hoist W_hh B-fragments in VGPRs (used 512x). Wave w owns, per gate,
    // the 32-col slice [w*32, w*32+32) -> n-tiles {g*8 + 2w, g*8 + 2w+1}.
    bf16x8 whhf[6][4];
#pragma unroll
    for (int ntl = 0; ntl < 6; ++ntl) {
        int gate = ntl >> 1, sub = ntl & 1;
        int n = gate * H + w * 32 + sub * 16 + ln;
        const float* p = Whh + (size_t)n * H;
#pragma unroll
        for (int ks = 0; ks < 4; ++ks) {
            const float* q = p + ks * 32 + quad * 8;
            bf16x8 f;
#pragma unroll
            for (int j = 0; j < 8; ++j) f[j] = (bf16_t)q[j];
            whhf[ntl][ks] = f;
        }
    }
    __syncthreads();

    for (int tc = 0; tc < NCHUNK; ++tc) {
        const int t0 = tc * CHUNK;

        // ================= phase A: MLP + gates for 64 rows (4b x 16t) ======
        // rr = b_local*16 + dt ; A-frag row m = ln = dt, M-tile mt = b_local.
        f32x4 vs[4][2];

        // ---- S1: h1 = LN(lrelu(x @ W1^T + b1)), N-split: wave w cols [w*32,w*32+32)
        {
            bf16x8 w1f[2][2];
#pragma unroll
            for (int ntl = 0; ntl < 2; ++ntl) {
                int n = w * 32 + ntl * 16 + ln;
                const float* p = W1 + (size_t)n * IN_DIM;
#pragma unroll
                for (int ks = 0; ks < 2; ++ks) {
                    const float* q = p + ks * 32 + quad * 8;
                    bf16x8 f;
#pragma unroll
                    for (int j = 0; j < 8; ++j) f[j] = (bf16_t)q[j];
                    w1f[ntl][ks] = f;
                }
            }
#pragma unroll
            for (int mt = 0; mt < 4; ++mt) {
                const float* xr_ = x + ((size_t)(b0 + mt) * Tt + t0 + ln) * IN_DIM;
                bf16x8 a0, a1;
#pragma unroll
                for (int j = 0; j < 8; ++j) {
                    a0[j] = (bf16_t)xr_[quad * 8 + j];
                    a1[j] = (bf16_t)xr_[32 + quad * 8 + j];
                }
#pragma unroll
                for (int ntl = 0; ntl < 2; ++ntl) {
                    f32x4 c = {0.f, 0.f, 0.f, 0.f};
                    c = MFMA(a0, w1f[ntl][0], c);
                    c = MFMA(a1, w1f[ntl][1], c);
                    vs[mt][ntl] = c;
                }
            }
            float bv[2], gv[2], bev[2];
#pragma unroll
            for (int ntl = 0; ntl < 2; ++ntl) {
                int n = w * 32 + ntl * 16 + ln;
                bv[ntl] = VEC[V_B1 + n]; gv[ntl] = VEC[V_G1 + n]; bev[ntl] = VEC[V_BE1 + n];
            }
#pragma unroll
            for (int mt = 0; mt < 4; ++mt) {
#pragma unroll
                for (int reg = 0; reg < 4; ++reg) {
                    float v0 = vs[mt][0][reg] + bv[0]; v0 = v0 > 0.f ? v0 : NEG * v0;
                    float v1 = vs[mt][1][reg] + bv[1]; v1 = v1 > 0.f ? v1 : NEG * v1;
                    vs[mt][0][reg] = v0; vs[mt][1][reg] = v1;
                    float s = v0 + v1, q = v0 * v0 + v1 * v1;
#pragma unroll
                    for (int d = 1; d < 16; d <<= 1) { s += __shfl_xor(s, d); q += __shfl_xor(q, d); }
                    if (ln == 0) {
                        int rr = mt * 16 + quad * 4 + reg;
                        RED[rr * 8 + w] = s; RED[rr * 8 + 4 + w] = q;
                    }
                }
            }
            __syncthreads();
            if (tid < 64) {
                float s = RED[tid * 8] + RED[tid * 8 + 1] + RED[tid * 8 + 2] + RED[tid * 8 + 3];
                float q = RED[tid * 8 + 4] + RED[tid * 8 + 5] + RED[tid * 8 + 6] + RED[tid * 8 + 7];
                float mean = s * (1.f / H);
                float var = q * (1.f / H) - mean * mean;
                MNR[tid * 2] = mean; MNR[tid * 2 + 1] = rsqrtf(var + EPSLN);
            }
            __syncthreads();
#pragma unroll
            for (int mt = 0; mt < 4; ++mt) {
#pragma unroll
                for (int reg = 0; reg < 4; ++reg) {
                    int rr = mt * 16 + quad * 4 + reg;
                    float mean = MNR[rr * 2], rstd = MNR[rr * 2 + 1];
#pragma unroll
                    for (int ntl = 0; ntl < 2; ++ntl) {
                        int n = w * 32 + ntl * 16 + ln;
                        HA[rr * HAS + n] = (bf16_t)(gv[ntl] * (vs[mt][ntl][reg] - mean) * rstd + bev[ntl]);
                    }
                }
            }
            __syncthreads();
        }

        // ---- S2: h2 = LN(lrelu(h1 @ W2^T + b2)) (K=128)
        {
            bf16x8 w2f[2][4];
#pragma unroll
            for (int ntl = 0; ntl < 2; ++ntl) {
                int n = w * 32 + ntl * 16 + ln;
                const float* p = W2 + (size_t)n * H;
#pragma unroll
                for (int ks = 0; ks < 4; ++ks) {
                    const float* q = p + ks * 32 + quad * 8;
                    bf16x8 f;
#pragma unroll
                    for (int j = 0; j < 8; ++j) f[j] = (bf16_t)q[j];
                    w2f[ntl][ks] = f;
                }
            }
#pragma unroll
            for (int mt = 0; mt < 4; ++mt) {
                bf16x8 af[4];
#pragma unroll
                for (int ks = 0; ks < 4; ++ks)
                    af[ks] = *(const bf16x8*)(HA + (mt * 16 + ln) * HAS + ks * 32 + quad * 8);
#pragma unroll
                for (int ntl = 0; ntl < 2; ++ntl) {
                    f32x4 c = {0.f, 0.f, 0.f, 0.f};
#pragma unroll
                    for (int ks = 0; ks < 4; ++ks) c = MFMA(af[ks], w2f[ntl][ks], c);
                    vs[mt][ntl] = c;
                }
            }
            float bv[2], gv[2], bev[2];
#pragma unroll
            for (int ntl = 0; ntl < 2; ++ntl) {
                int n = w * 32 + ntl * 16 + ln;
                bv[ntl] = VEC[V_B2 + n]; gv[ntl] = VEC[V_G2 + n]; bev[ntl] = VEC[V_BE2 + n];
            }
#pragma unroll
            for (int mt = 0; mt < 4; ++mt) {
#pragma unroll
                for (int reg = 0; reg < 4; ++reg) {
                    float v0 = vs[mt][0][reg] + bv[0]; v0 = v0 > 0.f ? v0 : NEG * v0;
                    float v1 = vs[mt][1][reg] + bv[1]; v1 = v1 > 0.f ? v1 : NEG * v1;
                    vs[mt][0][reg] = v0; vs[mt][1][reg] = v1;
                    float s = v0 + v1, q = v0 * v0 + v1 * v1;
#pragma unroll
                    for (int d = 1; d < 16; d <<= 1) { s += __shfl_xor(s, d); q += __shfl_xor(q, d); }
                    if (ln == 0) {
                        int rr = mt * 16 + quad * 4 + reg;
                        RED[rr * 8 + w] = s; RED[rr * 8 + 4 + w] = q;
                    }
                }
            }
            __syncthreads();
            if (tid < 64) {
                float s = RED[tid * 8] + RED[tid * 8 + 1] + RED[tid * 8 + 2] + RED[tid * 8 + 3];
                float q = RED[tid * 8 + 4] + RED[tid * 8 + 5] + RED[tid * 8 + 6] + RED[tid * 8 + 7];
                float mean = s * (1.f / H);
                float var = q * (1.f / H) - mean * mean;
                MNR[tid * 2] = mean; MNR[tid * 2 + 1] = rsqrtf(var + EPSLN);
            }
            __syncthreads();
#pragma unroll
            for (int mt = 0; mt < 4; ++mt) {
#pragma unroll
                for (int reg = 0; reg < 4; ++reg) {
                    int rr = mt * 16 + quad * 4 + reg;
                    float mean = MNR[rr * 2], rstd = MNR[rr * 2 + 1];
#pragma unroll
                    for (int ntl = 0; ntl < 2; ++ntl) {
                        int n = w * 32 + ntl * 16 + ln;
                        HA[rr * HAS + n] = (bf16_t)(gv[ntl] * (vs[mt][ntl][reg] - mean) * rstd + bev[ntl]);
                    }
                }
            }
            __syncthreads();
        }

        // ---- S3: gx = h2 @ W_ih^T + b_ih  -> GX tile (bf16). wave w: n-tiles [6w,6w+6)
        for (int ntl = 0; ntl < 6; ++ntl) {
            int n = (w * 6 + ntl) * 16 + ln;
            const float* p = Wih + (size_t)n * H;
            bf16x8 bf[4];
#pragma unroll
            for (int ks = 0; ks < 4; ++ks) {
                const float* q = p + ks * 32 + quad * 8;
                bf16x8 f;
#pragma unroll
                for (int j = 0; j < 8; ++j) f[j] = (bf16_t)q[j];
                bf[ks] = f;
            }
            float bv = VEC[V_BIH + n];
#pragma unroll
            for (int mt = 0; mt < 4; ++mt) {
                bf16x8 af[4];
#pragma unroll
                for (int ks = 0; ks < 4; ++ks)
                    af[ks] = *(const bf16x8*)(HA + (mt * 16 + ln) * HAS + ks * 32 + quad * 8);
                f32x4 c = {0.f, 0.f, 0.f, 0.f};
#pragma unroll
                for (int ks = 0; ks < 4; ++ks) c = MFMA(af[ks], bf[ks], c);
#pragma unroll
                for (int reg = 0; reg < 4; ++reg)
                    GX[(mt * 16 + quad * 4 + reg) * GXS + n] = (bf16_t)(c[reg] + bv);
            }
        }
        // init flags for this chunk (+1 lookahead)
        if (tid < 68) {
            int b = tid / 17, s = tid % 17;
            int t = t0 + s;
            INI[tid] = (t < Tt) ? is_init[(size_t)(b0 + b) * Tt + t] : 0;
        }

        // ================= recurrent: 16 GRU steps ==========================
        for (int s = 0; s < CHUNK; ++s) {
            __syncthreads();   // h_prev/GX/INI visible; GHB free
            // gh = h_prev @ W_hh^T  (M=16, rows 0..3 valid)
            bf16x8 af[4];
#pragma unroll
            for (int ks = 0; ks < 4; ++ks)
                af[ks] = *(const bf16x8*)(HPB + ln * HAS + ks * 32 + quad * 8);
            f32x4 gc[6];
#pragma unroll
            for (int ntl = 0; ntl < 6; ++ntl) {
                f32x4 c = {0.f, 0.f, 0.f, 0.f};
#pragma unroll
                for (int ks = 0; ks < 4; ++ks) c = MFMA(af[ks], whhf[ntl][ks], c);
                gc[ntl] = c;
            }
            if (quad == 0) {  // quad 0 holds C rows 0..3 (= the 4 batch rows)
#pragma unroll
                for (int ntl = 0; ntl < 6; ++ntl) {
                    int gate = ntl >> 1, sub = ntl & 1;
                    int n = gate * H + w * 32 + sub * 16 + ln;
#pragma unroll
                    for (int reg = 0; reg < 4; ++reg)
                        GHB[reg * GHS + n] = gc[ntl][reg];
                }
            }
            __syncthreads();
            const int t = t0 + s;
#pragma unroll
            for (int rep = 0; rep < 2; ++rep) {
                int job = tid + rep * 256;
                int b = job >> 7, j = job & 127;
                int rrow = b * 16 + s;
                float xr = (float)GX[rrow * GXS + j];
                float xz = (float)GX[rrow * GXS + H + j];
                float xn = (float)GX[rrow * GXS + 2 * H + j];
                float hr = GHB[b * GHS + j]         + VEC[V_BHH + j];
                float hz = GHB[b * GHS + H + j]     + VEC[V_BHH + H + j];
                float hn = GHB[b * GHS + 2 * H + j] + VEC[V_BHH + 2 * H + j];
                float r = 1.f / (1.f + __expf(-(xr + hr)));
                float z = 1.f / (1.f + __expf(-(xz + hz)));
                float a = xn + r * hn;
                a = fminf(fmaxf(a, -15.f), 15.f);
                float e = __expf(-2.f * a);
                float nn = (1.f - e) / (1.f + e);
                float hp = HPF[b * H + j];
                float hnew = (1.f - z) * nn + z * hp;
                HA[rrow * HAS + j] = (bf16_t)hnew;          // y for out-proj
                float hm;
                if (t < Tt - 1) {
                    hm = INI[b * 17 + s + 1] ? 0.f : hnew;  // fold next-step reset
                } else {
                    hm = hnew;
                    out[(size_t)Bb * Tt * OUT_DIM + (size_t)(b0 + b) * H + j] = hnew;
                }
                HPF[b * H + j] = hm;
                HPB[b * HAS + j] = (bf16_t)hm;
            }
        }
        __syncthreads();

        // ================= out-projection: y @ W_out^T + b_out ==============
        {
            int o = w * 16 + ln;
            const float* p = Wout + (size_t)o * H;
            bf16x8 wof[4];
#pragma unroll
            for (int ks = 0; ks < 4; ++ks) {
                const float* q = p + ks * 32 + quad * 8;
                bf16x8 f;
#pragma unroll
                for (int j = 0; j < 8; ++j) f[j] = (bf16_t)q[j];
                wof[ks] = f;
            }
            float bo = VEC[V_BOUT + o];
#pragma unroll
            for (int mt = 0; mt < 4; ++mt) {
                bf16x8 af[4];
#pragma unroll
                for (int ks = 0; ks < 4; ++ks)
                    af[ks] = *(const bf16x8*)(HA + (mt * 16 + ln) * HAS + ks * 32 + quad * 8);
                f32x4 c = {0.f, 0.f, 0.f, 0.f};
#pragma unroll
                for (int ks = 0; ks < 4; ++ks) c = MFMA(af[ks], wof[ks], c);
#pragma unroll
                for (int reg = 0; reg < 4; ++reg)
                    out[((size_t)(b0 + mt) * Tt + t0 + quad * 4 + reg) * OUT_DIM + o] = c[reg] + bo;
            }
        }
        __syncthreads();  // protect HA reuse next chunk
    }
}

extern "C" void kernel_launch(void* const* d_in, const int* in_sizes, int n_in,
                              void* d_out, int out_size, void* d_ws, size_t ws_size,
                              hipStream_t stream) {
    const float* x      = (const float*)d_in[0];
    const int*   is_init= (const int*)  d_in[1];
    const float* hx     = (const float*)d_in[2];
    const float* W1     = (const float*)d_in[3];
    const float* b1     = (const float*)d_in[4];
    const float* g1     = (const float*)d_in[5];
    const float* be1    = (const float*)d_in[6];
    const float* W2     = (const float*)d_in[7];
    const float* b2     = (const float*)d_in[8];
    const float* g2     = (const float*)d_in[9];
    const float* be2    = (const float*)d_in[10];
    const float* Wih    = (const float*)d_in[11];
    const float* Whh    = (const float*)d_in[12];
    const float* bih    = (const float*)d_in[13];
    const float* bhh    = (const float*)d_in[14];
    const float* Wout   = (const float*)d_in[15];
    const float* bout   = (const float*)d_in[16];
    float* out = (float*)d_out;

    hipFuncSetAttribute((const void*)gru_fused,
                        hipFuncAttributeMaxDynamicSharedMemorySize, SMEM_BYTES);
    gru_fused<<<Bb / 4, 256, SMEM_BYTES, stream>>>(
        x, is_init, hx, W1, b1, g1, be1, W2, b2, g2, be2,
        Wih, Whh, bih, bhh, Wout, bout, out);
}